// Round 2
// baseline (162.157 us; speedup 1.0000x reference)
//
#include <hip/hip_runtime.h>
#include <cmath>

#define NN 50000
#define NE 800000
#define INC 128
#define C1 256
#define O2 64
#define NG 64
#define NSLOT 16      // pooling atomic slots
#define NBKT 196      // CSR sort buckets: 256 dsts each
#define CHUNK 2048    // edges per binA block
#define NBA ((NE + CHUNK - 1) / CHUNK)   // 391 binA sort blocks
#define SUMW (NSLOT * NG * O2)           // 65536 words
#define SUMQ (SUMW / 4)                  // 16384 quads -> 64 blocks
#define PB_HB 256     // histogram blocks in prep
#define EPB (NE / PB_HB)  // 3125 edges per hist block (exact)
#define PB_W 193      // W-transpose + bounds blocks

typedef short bf16x8 __attribute__((ext_vector_type(8)));
typedef float f32x4 __attribute__((ext_vector_type(4)));
typedef float f32x2 __attribute__((ext_vector_type(2)));

__device__ __forceinline__ float lrelu02(float x) { return x >= 0.f ? x : 0.2f * x; }
__device__ __forceinline__ float eluf(float x) { return x > 0.f ? x : expm1f(x); }
__device__ __forceinline__ unsigned short f2bf(float f) {
    unsigned u = __float_as_uint(f);
    u += 0x7fffu + ((u >> 16) & 1u);
    return (unsigned short)(u >> 16);
}
__device__ __forceinline__ float bf2f(unsigned short s) {
    return __uint_as_float(((unsigned)s) << 16);
}

// ---- fp8 e4m3 encode/decode (HW converts on gfx950; SW fallback) ----
__device__ __forceinline__ unsigned char f2fp8(float f) {
#if __has_builtin(__builtin_amdgcn_cvt_pk_fp8_f32)
    return (unsigned char)(__builtin_amdgcn_cvt_pk_fp8_f32(f, f, 0, false) & 0xff);
#else
    unsigned u = __float_as_uint(f);
    unsigned s = u >> 31;
    float a = fabsf(f);
    int e = ((u >> 23) & 255) - 127;
    if (e < -6) {
        int q = (int)rintf(ldexpf(a, 9));
        return (unsigned char)((s << 7) | (unsigned)q);
    }
    unsigned m = u & 0x7fffffu;
    const unsigned keep = 20;
    unsigned mr = m + ((1u << (keep - 1)) - 1 + ((m >> keep) & 1));
    if (mr >> 23) { e += 1; mr = 0; }
    unsigned m3 = (mr >> keep) & 7;
    if (e > 8) { e = 8; m3 = 6; }
    return (unsigned char)((s << 7) | ((unsigned)(e + 7) << 3) | m3);
#endif
}
__device__ __forceinline__ float fp81(unsigned b) {
#if __has_builtin(__builtin_amdgcn_cvt_f32_fp8)
    return __builtin_amdgcn_cvt_f32_fp8((int)b, 0);
#else
    unsigned s = (b >> 7) & 1, e = (b >> 3) & 15, m = b & 7;
    float v = (e == 0) ? ldexpf((float)m, -9) : ldexpf((float)(8 + m), (int)e - 10);
    return s ? -v : v;
#endif
}
__device__ __forceinline__ float4 fp8x4(unsigned uu) {
#if __has_builtin(__builtin_amdgcn_cvt_pk_f32_fp8)
    f32x2 lo = __builtin_amdgcn_cvt_pk_f32_fp8(uu, false);
    f32x2 hi = __builtin_amdgcn_cvt_pk_f32_fp8(uu, true);
    return make_float4(lo[0], lo[1], hi[0], hi[1]);
#else
    return make_float4(fp81(uu & 255), fp81((uu >> 8) & 255),
                       fp81((uu >> 16) & 255), fp81(uu >> 24));
#endif
}

// ---- zero bh|gcur (512 words = 128 quads, one block) ----
__global__ __launch_bounds__(128) void gat_zero(float4* __restrict__ z) {
    z[threadIdx.x] = make_float4(0.f, 0.f, 0.f, 0.f);
}

// ---- fused prep: [0,256) bucket histogram (196 buckets) | [256,449) W transpose + bounds ----
__global__ __launch_bounds__(256) void gat_prep(const int* __restrict__ ei,
                                                const float* __restrict__ W1,
                                                const float* __restrict__ W2,
                                                const int* __restrict__ batch,
                                                int* __restrict__ bh,
                                                unsigned short* __restrict__ w1t,
                                                unsigned short* __restrict__ w2t,
                                                int* __restrict__ bnds) {
    int b = blockIdx.x, t = threadIdx.x;
    if (b < PB_HB) {
        __shared__ int h[256];
        h[t] = 0;
        __syncthreads();
        int j0 = b * EPB;
        for (int k = t; k < EPB; k += 256)
            atomicAdd(&h[ei[NE + j0 + k] >> 8], 1);
        __syncthreads();
        if (t < NBKT && h[t] > 0) atomicAdd(bh + t, h[t]);
    } else {
        int bb_ = b - PB_HB;
        if (bb_ < 128) {                     // w1t[256][128] = W1^T
            int idx = bb_ * 256 + t;
            int n = idx >> 7, k = idx & 127;
            w1t[idx] = f2bf(W1[(size_t)k * C1 + n]);
        } else if (bb_ < 192) {              // w2t[64][256] = W2^T
            int idx = (bb_ - 128) * 256 + t;
            int n = idx >> 8, k = idx & 255;
            w2t[idx] = f2bf(W2[(size_t)k * O2 + n]);
        } else {
            if (t <= NG) {
                int lo = 0, hi = NN;
                while (lo < hi) {
                    int mid = (lo + hi) >> 1;
                    if (batch[mid] < t) lo = mid + 1; else hi = mid;
                }
                bnds[t] = lo;
            }
        }
    }
}

// ---- scan of 196 bucket counts -> bucket bases bb[0..196] ----
__global__ __launch_bounds__(256) void gat_scanb(const int* __restrict__ bh,
                                                 int* __restrict__ bb) {
    __shared__ int lds[256];
    int t = threadIdx.x;
    int v = (t < NBKT) ? bh[t] : 0;
    lds[t] = v;
    __syncthreads();
#pragma unroll
    for (int o = 1; o < 256; o <<= 1) {
        int add = (t >= o) ? lds[t - o] : 0;
        __syncthreads();
        lds[t] += add;
        __syncthreads();
    }
    if (t <= NBKT) bb[t] = lds[t] - v;   // exclusive; bb[196] = NE
}

// ---- CSR build phase A: counting sort by bucket; extra blocks zero `sums` ----
__global__ __launch_bounds__(256) void gat_binA(const int* __restrict__ ei,
                                                const int* __restrict__ bb,
                                                int* __restrict__ gcur,
                                                unsigned* __restrict__ ebuf,
                                                float4* __restrict__ sumsq) {
    __shared__ int hist[256], lofs[256], gofs[256], fill[256];
    __shared__ unsigned stage[CHUNK];
    const int t = threadIdx.x;
    if (blockIdx.x >= NBA) {                 // sums-zero blocks (overlapped with sort)
        int i = (blockIdx.x - NBA) * 256 + t;
        sumsq[i] = make_float4(0.f, 0.f, 0.f, 0.f);
        return;
    }
    const int j0 = blockIdx.x * CHUNK;
    const int n = min(CHUNK, NE - j0);
    hist[t] = 0;
    __syncthreads();
    for (int k = t; k < n; k += 256)
        atomicAdd(&hist[ei[NE + j0 + k] >> 8], 1);
    __syncthreads();
    int v = hist[t];
    lofs[t] = v;
    __syncthreads();
#pragma unroll
    for (int o = 1; o < 256; o <<= 1) {
        int add = (t >= o) ? lofs[t - o] : 0;
        __syncthreads();
        lofs[t] += add;
        __syncthreads();
    }
    int excl = lofs[t] - v;
    __syncthreads();
    lofs[t] = excl;
    if (t < NBKT && v > 0)
        gofs[t] = bb[t] + atomicAdd(gcur + t, v);
    fill[t] = 0;
    __syncthreads();
    for (int k = t; k < n; k += 256) {
        int j = j0 + k;
        int d = ei[NE + j];
        int s = ei[j];
        int b = d >> 8;
        int r = atomicAdd(&fill[b], 1);
        stage[lofs[b] + r] = (unsigned)s | ((unsigned)(d & 255) << 16) | ((unsigned)b << 24);
    }
    __syncthreads();
    for (int idx = t; idx < n; idx += 256) {
        unsigned u = stage[idx];
        int b = u >> 24;
        ebuf[gofs[b] + (idx - lofs[b])] = u;
    }
}

// ---- merged launch: blocks [0,NBKT) = binB (per-dst rowptr + placement);
//      blocks [NBKT, ...) = gemm1 ----
__global__ __launch_bounds__(256) void gat_binB_gemm1(
        const unsigned* __restrict__ ebuf, const int* __restrict__ bb,
        int* __restrict__ rowptr, int* __restrict__ csrs,
        const float* __restrict__ x, const unsigned short* __restrict__ w1t,
        const float* __restrict__ as1, const float* __restrict__ ad1,
        unsigned char* __restrict__ h1f8, float* __restrict__ aS,
        float* __restrict__ aD) {
    __shared__ unsigned short As[64][136];
    __shared__ unsigned short Bh[64][136];
    __shared__ int cntB[256];
    __shared__ int scB[256];
    const int tid = threadIdx.x;
    if (blockIdx.x < NBKT) {
        const int b = blockIdx.x, t = tid;
        const int base = bb[b], end = bb[b + 1];
        cntB[t] = 0;
        __syncthreads();
        for (int idx = base + t; idx < end; idx += 256)
            atomicAdd(&cntB[(ebuf[idx] >> 16) & 255], 1);
        __syncthreads();
        int v = cntB[t];
        scB[t] = v;
        __syncthreads();
#pragma unroll
        for (int o = 1; o < 256; o <<= 1) {
            int add = (t >= o) ? scB[t - o] : 0;
            __syncthreads();
            scB[t] += add;
            __syncthreads();
        }
        int rp = base + scB[t] - v;      // global CSR start for dst (b<<8)+t
        __syncthreads();
        scB[t] = rp;
        int d = (b << 8) + t;
        if (d < NN) rowptr[d] = rp;
        if (b == 0 && t == 0) rowptr[NN] = NE;
        cntB[t] = 0;
        __syncthreads();
        for (int idx = base + t; idx < end; idx += 256) {
            unsigned u = ebuf[idx];
            int dl = (u >> 16) & 255;
            int s = (int)(u & 0xffffu);
            int r = atomicAdd(&cntB[dl], 1);
            csrs[scB[dl] + r] = s;
        }
        return;
    }
    const int m0 = (blockIdx.x - NBKT) * 64;
    const int seg = tid & 15, r = tid >> 4;
#pragma unroll
    for (int i = 0; i < 4; ++i) {
        int rr = r + i * 16, gr = m0 + rr;
        ushort4 o0 = {0, 0, 0, 0}, o1 = {0, 0, 0, 0};
        if (gr < NN) {
            const float* p = x + (size_t)gr * INC + seg * 8;
            float4 v0 = *(const float4*)p;
            float4 v1 = *(const float4*)(p + 4);
            o0.x = f2bf(v0.x); o0.y = f2bf(v0.y); o0.z = f2bf(v0.z); o0.w = f2bf(v0.w);
            o1.x = f2bf(v1.x); o1.y = f2bf(v1.y); o1.z = f2bf(v1.z); o1.w = f2bf(v1.w);
        }
        *(ushort4*)&As[rr][seg * 8] = o0;
        *(ushort4*)&As[rr][seg * 8 + 4] = o1;
    }
    __syncthreads();
    const int lane = tid & 63, w = tid >> 6;
    const int lr = lane & 15, lk = (lane >> 4) * 8;
    bf16x8 a[4];
#pragma unroll
    for (int q = 0; q < 4; ++q)
        a[q] = *(const bf16x8*)&As[w * 16 + lr][q * 32 + lk];
    const int rbase = m0 + w * 16 + (lane >> 4) * 4;
    float psH[2][4] = {}, pdH[2][4] = {};
    for (int it = 0; it < 4; ++it) {
        const int n0 = it * 64;
        if (it > 0) __syncthreads();
        {
#pragma unroll
            for (int i = 0; i < 4; ++i) {
                int nr = r + i * 16;
                *(int4*)&Bh[nr][seg * 8] = *(const int4*)(w1t + (size_t)(n0 + nr) * INC + seg * 8);
            }
        }
        __syncthreads();
        f32x4 acc[4] = {};
#pragma unroll
        for (int j = 0; j < 4; ++j) {
#pragma unroll
            for (int q = 0; q < 4; ++q) {
                bf16x8 bh = *(const bf16x8*)&Bh[j * 16 + lr][q * 32 + lk];
                acc[j] = __builtin_amdgcn_mfma_f32_16x16x32_bf16(a[q], bh, acc[j], 0, 0, 0);
            }
        }
#pragma unroll
        for (int j = 0; j < 4; ++j) {
            int col = n0 + j * 16 + lr;
#pragma unroll
            for (int r4 = 0; r4 < 4; ++r4) {
                int gr = rbase + r4;
                if (gr < NN) h1f8[(size_t)gr * C1 + col] = f2fp8(acc[j][r4]);
            }
        }
        const int head = n0 >> 7;
        float attS[4], attD[4];
#pragma unroll
        for (int j = 0; j < 4; ++j) {
            attS[j] = as1[n0 + j * 16 + lr];
            attD[j] = ad1[n0 + j * 16 + lr];
        }
#pragma unroll
        for (int r4 = 0; r4 < 4; ++r4) {
#pragma unroll
            for (int j = 0; j < 4; ++j) {
                psH[head][r4] = fmaf(acc[j][r4], attS[j], psH[head][r4]);
                pdH[head][r4] = fmaf(acc[j][r4], attD[j], pdH[head][r4]);
            }
        }
    }
#pragma unroll
    for (int r4 = 0; r4 < 4; ++r4) {
        float p0 = psH[0][r4], p1 = psH[1][r4];
        float d0 = pdH[0][r4], d1 = pdH[1][r4];
#pragma unroll
        for (int o = 1; o < 16; o <<= 1) {
            p0 += __shfl_xor(p0, o, 64);
            p1 += __shfl_xor(p1, o, 64);
            d0 += __shfl_xor(d0, o, 64);
            d1 += __shfl_xor(d1, o, 64);
        }
        if (lr == 0) {
            int gr = rbase + r4;
            if (gr < NN) {
                *(float2*)(aS + (size_t)gr * 2) = make_float2(p0, p1);
                *(float2*)(aD + (size_t)gr * 2) = make_float2(d0, d1);
            }
        }
    }
}

// --- GEMM2 (MFMA) + fused att2 (full row per block, direct store); h2 out fp8 ---
__global__ __launch_bounds__(256) void gat_gemm2(const unsigned short* __restrict__ out1b,
                                                 const float* __restrict__ b1,
                                                 const unsigned short* __restrict__ w2t,
                                                 const float* __restrict__ as2,
                                                 const float* __restrict__ ad2,
                                                 unsigned char* __restrict__ h2f8,
                                                 float* __restrict__ aS,
                                                 float* __restrict__ aD) {
    __shared__ unsigned short As[64][136];
    __shared__ unsigned short Bh[64][136];
    const int m0 = blockIdx.x * 64;
    const int tid = threadIdx.x;
    const int lane = tid & 63, w = tid >> 6;
    const int lr = lane & 15, lk = (lane >> 4) * 8;
    f32x4 acc[4] = {};
    for (int kc = 0; kc < 2; ++kc) {
        __syncthreads();
        {
            int seg = tid & 15, r = tid >> 4;
            float4 bia0 = *(const float4*)(b1 + kc * 128 + seg * 8);
            float4 bia1 = *(const float4*)(b1 + kc * 128 + seg * 8 + 4);
#pragma unroll
            for (int i = 0; i < 4; ++i) {
                int rr = r + i * 16, gr = m0 + rr;
                ushort4 o0 = {0, 0, 0, 0}, o1 = {0, 0, 0, 0};
                if (gr < NN) {
                    const unsigned short* p = out1b + (size_t)gr * C1 + kc * 128 + seg * 8;
                    ushort4 u0 = *(const ushort4*)p;
                    ushort4 u1 = *(const ushort4*)(p + 4);
                    o0.x = f2bf(eluf(bf2f(u0.x) + bia0.x));
                    o0.y = f2bf(eluf(bf2f(u0.y) + bia0.y));
                    o0.z = f2bf(eluf(bf2f(u0.z) + bia0.z));
                    o0.w = f2bf(eluf(bf2f(u0.w) + bia0.w));
                    o1.x = f2bf(eluf(bf2f(u1.x) + bia1.x));
                    o1.y = f2bf(eluf(bf2f(u1.y) + bia1.y));
                    o1.z = f2bf(eluf(bf2f(u1.z) + bia1.z));
                    o1.w = f2bf(eluf(bf2f(u1.w) + bia1.w));
                }
                *(ushort4*)&As[rr][seg * 8] = o0;
                *(ushort4*)&As[rr][seg * 8 + 4] = o1;
            }
#pragma unroll
            for (int i = 0; i < 4; ++i) {
                int nr = r + i * 16;
                *(int4*)&Bh[nr][seg * 8] = *(const int4*)(w2t + (size_t)nr * C1 + kc * 128 + seg * 8);
            }
        }
        __syncthreads();
        bf16x8 a[4];
#pragma unroll
        for (int q = 0; q < 4; ++q)
            a[q] = *(const bf16x8*)&As[w * 16 + lr][q * 32 + lk];
#pragma unroll
        for (int j = 0; j < 4; ++j) {
#pragma unroll
            for (int q = 0; q < 4; ++q) {
                bf16x8 bh = *(const bf16x8*)&Bh[j * 16 + lr][q * 32 + lk];
                acc[j] = __builtin_amdgcn_mfma_f32_16x16x32_bf16(a[q], bh, acc[j], 0, 0, 0);
            }
        }
    }
    const int rbase = m0 + w * 16 + (lane >> 4) * 4;
#pragma unroll
    for (int j = 0; j < 4; ++j) {
        int col = j * 16 + lr;
#pragma unroll
        for (int r4 = 0; r4 < 4; ++r4) {
            int gr = rbase + r4;
            if (gr < NN) h2f8[(size_t)gr * O2 + col] = f2fp8(acc[j][r4]);
        }
    }
    float attS[4], attD[4];
#pragma unroll
    for (int j = 0; j < 4; ++j) {
        attS[j] = as2[j * 16 + lr];
        attD[j] = ad2[j * 16 + lr];
    }
#pragma unroll
    for (int r4 = 0; r4 < 4; ++r4) {
        float ps = 0.f, pd = 0.f;
#pragma unroll
        for (int j = 0; j < 4; ++j) {
            ps = fmaf(acc[j][r4], attS[j], ps);
            pd = fmaf(acc[j][r4], attD[j], pd);
        }
#pragma unroll
        for (int o = 1; o < 16; o <<= 1) {
            ps += __shfl_xor(ps, o, 64);
            pd += __shfl_xor(pd, o, 64);
        }
        if (lr == 0) {
            int gr = rbase + r4;
            if (gr < NN) { aS[gr] = ps; aD[gr] = pd; }
        }
    }
}

// ------- aggregation layer 1: 1 dst/wave, 2 edge sub-slices x 32 channel-lanes,
//         redundant per-lane e (no shuffles), 4-way unrolled clamp+mask chains -------
__global__ __launch_bounds__(256) void gat_agg1(const int* __restrict__ rowptr,
                                                const int* __restrict__ csrs,
                                                const float* __restrict__ aS,
                                                const float* __restrict__ aD,
                                                const unsigned char* __restrict__ h1f8,
                                                unsigned short* __restrict__ out1b) {
    const int wid = threadIdx.x >> 6, lane = threadIdx.x & 63;
    const int sub = lane >> 5;             // edge sub-slice 0..1
    const int li = lane & 31;              // channel lane
    const int head = li >> 4;              // 0: ch<128, 1: ch>=128
    const int ch = li << 3;                // 8 fp8 channels per lane
    const int d = blockIdx.x * 4 + wid;    // 12500 blocks * 4 = 50000 exact
    const int st = rowptr[d], en = rowptr[d + 1];
    const float adv = aD[2 * (size_t)d + head];
    const float* aSh = aS + head;
    const unsigned char* hrow = h1f8 + ch;
    float a0 = 0.f, a1 = 0.f, a2 = 0.f, a3 = 0.f;
    float a4 = 0.f, a5 = 0.f, a6 = 0.f, a7 = 0.f;
    float sd = 0.f;
    const int en1 = en - 1;
    for (int i = st + sub; i < en; i += 8) {
        const int i1 = i + 2, i2 = i + 4, i3 = i + 6;
        int s0 = csrs[i];
        int s1 = csrs[min(i1, en1)];
        int s2 = csrs[min(i2, en1)];
        int s3 = csrs[min(i3, en1)];
        float x0 = aSh[2 * (size_t)s0];
        float x1 = aSh[2 * (size_t)s1];
        float x2 = aSh[2 * (size_t)s2];
        float x3 = aSh[2 * (size_t)s3];
        uint2 u0 = *(const uint2*)(hrow + (size_t)s0 * C1);
        uint2 u1 = *(const uint2*)(hrow + (size_t)s1 * C1);
        uint2 u2 = *(const uint2*)(hrow + (size_t)s2 * C1);
        uint2 u3 = *(const uint2*)(hrow + (size_t)s3 * C1);
        float e0 = __expf(lrelu02(x0 + adv));
        float e1 = (i1 < en) ? __expf(lrelu02(x1 + adv)) : 0.f;
        float e2 = (i2 < en) ? __expf(lrelu02(x2 + adv)) : 0.f;
        float e3 = (i3 < en) ? __expf(lrelu02(x3 + adv)) : 0.f;
        sd += (e0 + e1) + (e2 + e3);
        float4 w0, w1;
        w0 = fp8x4(u0.x); w1 = fp8x4(u0.y);
        a0 = fmaf(w0.x, e0, a0); a1 = fmaf(w0.y, e0, a1);
        a2 = fmaf(w0.z, e0, a2); a3 = fmaf(w0.w, e0, a3);
        a4 = fmaf(w1.x, e0, a4); a5 = fmaf(w1.y, e0, a5);
        a6 = fmaf(w1.z, e0, a6); a7 = fmaf(w1.w, e0, a7);
        w0 = fp8x4(u1.x); w1 = fp8x4(u1.y);
        a0 = fmaf(w0.x, e1, a0); a1 = fmaf(w0.y, e1, a1);
        a2 = fmaf(w0.z, e1, a2); a3 = fmaf(w0.w, e1, a3);
        a4 = fmaf(w1.x, e1, a4); a5 = fmaf(w1.y, e1, a5);
        a6 = fmaf(w1.z, e1, a6); a7 = fmaf(w1.w, e1, a7);
        w0 = fp8x4(u2.x); w1 = fp8x4(u2.y);
        a0 = fmaf(w0.x, e2, a0); a1 = fmaf(w0.y, e2, a1);
        a2 = fmaf(w0.z, e2, a2); a3 = fmaf(w0.w, e2, a3);
        a4 = fmaf(w1.x, e2, a4); a5 = fmaf(w1.y, e2, a5);
        a6 = fmaf(w1.z, e2, a6); a7 = fmaf(w1.w, e2, a7);
        w0 = fp8x4(u3.x); w1 = fp8x4(u3.y);
        a0 = fmaf(w0.x, e3, a0); a1 = fmaf(w0.y, e3, a1);
        a2 = fmaf(w0.z, e3, a2); a3 = fmaf(w0.w, e3, a3);
        a4 = fmaf(w1.x, e3, a4); a5 = fmaf(w1.y, e3, a5);
        a6 = fmaf(w1.z, e3, a6); a7 = fmaf(w1.w, e3, a7);
    }
    // combine the two edge sub-slices (lane ^ 32 has same channels/head)
    a0 += __shfl_xor(a0, 32, 64); a1 += __shfl_xor(a1, 32, 64);
    a2 += __shfl_xor(a2, 32, 64); a3 += __shfl_xor(a3, 32, 64);
    a4 += __shfl_xor(a4, 32, 64); a5 += __shfl_xor(a5, 32, 64);
    a6 += __shfl_xor(a6, 32, 64); a7 += __shfl_xor(a7, 32, 64);
    sd += __shfl_xor(sd, 32, 64);
    float inv = 1.f / (sd + 1e-16f);
    // sub 0 writes channels [ch, ch+4), sub 1 writes [ch+4, ch+8)
    float r0 = sub ? a4 : a0, r1 = sub ? a5 : a1;
    float r2 = sub ? a6 : a2, r3 = sub ? a7 : a3;
    ushort4 o;
    o.x = f2bf(r0 * inv); o.y = f2bf(r1 * inv);
    o.z = f2bf(r2 * inv); o.w = f2bf(r3 * inv);
    *(ushort4*)(out1b + (size_t)d * C1 + ch + (sub << 2)) = o;
}

// ------- aggregation layer 2: 1 dst/wave, 4 edge sub-slices x 16 channel-lanes,
//         redundant per-lane e, 4-way unroll; pooling via LDS transpose (1 atomic/thread) -------
__global__ __launch_bounds__(256) void gat_agg2(const int* __restrict__ rowptr,
                                                const int* __restrict__ csrs,
                                                const float* __restrict__ aS,
                                                const float* __restrict__ aD,
                                                const unsigned char* __restrict__ h2f8,
                                                const int* __restrict__ batch,
                                                const float* __restrict__ b2,
                                                float* __restrict__ sums) {
    __shared__ float pool[4][64];
    const int wid = threadIdx.x >> 6, lane = threadIdx.x & 63;
    const int sub = lane >> 4;             // edge sub-slice 0..3
    const int li = lane & 15;              // channel lane
    const int c = li << 2;                 // 4 channels per lane
    const int d = blockIdx.x * 4 + wid;    // 12500 blocks * 4 = 50000 exact
    const int st = rowptr[d], en = rowptr[d + 1];
    const float adv = aD[d];
    const unsigned char* hrow = h2f8 + c;
    float a0 = 0.f, a1 = 0.f, a2 = 0.f, a3 = 0.f;
    float sd = 0.f;
    const int en1 = en - 1;
    for (int i = st + sub; i < en; i += 16) {
        const int i1 = i + 4, i2 = i + 8, i3 = i + 12;
        int s0 = csrs[i];
        int s1 = csrs[min(i1, en1)];
        int s2 = csrs[min(i2, en1)];
        int s3 = csrs[min(i3, en1)];
        float x0 = aS[s0];
        float x1 = aS[s1];
        float x2 = aS[s2];
        float x3 = aS[s3];
        unsigned u0 = *(const unsigned*)(hrow + (size_t)s0 * O2);
        unsigned u1 = *(const unsigned*)(hrow + (size_t)s1 * O2);
        unsigned u2 = *(const unsigned*)(hrow + (size_t)s2 * O2);
        unsigned u3 = *(const unsigned*)(hrow + (size_t)s3 * O2);
        float e0 = __expf(lrelu02(x0 + adv));
        float e1 = (i1 < en) ? __expf(lrelu02(x1 + adv)) : 0.f;
        float e2 = (i2 < en) ? __expf(lrelu02(x2 + adv)) : 0.f;
        float e3 = (i3 < en) ? __expf(lrelu02(x3 + adv)) : 0.f;
        sd += (e0 + e1) + (e2 + e3);
        float4 v;
        v = fp8x4(u0);
        a0 = fmaf(v.x, e0, a0); a1 = fmaf(v.y, e0, a1);
        a2 = fmaf(v.z, e0, a2); a3 = fmaf(v.w, e0, a3);
        v = fp8x4(u1);
        a0 = fmaf(v.x, e1, a0); a1 = fmaf(v.y, e1, a1);
        a2 = fmaf(v.z, e1, a2); a3 = fmaf(v.w, e1, a3);
        v = fp8x4(u2);
        a0 = fmaf(v.x, e2, a0); a1 = fmaf(v.y, e2, a1);
        a2 = fmaf(v.z, e2, a2); a3 = fmaf(v.w, e2, a3);
        v = fp8x4(u3);
        a0 = fmaf(v.x, e3, a0); a1 = fmaf(v.y, e3, a1);
        a2 = fmaf(v.z, e3, a2); a3 = fmaf(v.w, e3, a3);
    }
    // combine the four edge sub-slices (lanes ^16, ^32 have same channels)
    a0 += __shfl_xor(a0, 16, 64); a0 += __shfl_xor(a0, 32, 64);
    a1 += __shfl_xor(a1, 16, 64); a1 += __shfl_xor(a1, 32, 64);
    a2 += __shfl_xor(a2, 16, 64); a2 += __shfl_xor(a2, 32, 64);
    a3 += __shfl_xor(a3, 16, 64); a3 += __shfl_xor(a3, 32, 64);
    sd += __shfl_xor(sd, 16, 64); sd += __shfl_xor(sd, 32, 64);
    float inv = 1.f / (sd + 1e-16f);
    if (sub == 0)
        *(float4*)&pool[wid][c] = make_float4(a0 * inv, a1 * inv, a2 * inv, a3 * inv);
    __syncthreads();
    const int slot = blockIdx.x & (NSLOT - 1);
    const int r = threadIdx.x >> 6;        // row within block
    const int chn = threadIdx.x & 63;
    const int dr = blockIdx.x * 4 + r;
    float v = pool[r][chn] + b2[chn];
    v = (v > 0.f) ? v : expm1f(v);
    unsafeAtomicAdd(sums + ((size_t)slot * NG + batch[dr]) * O2 + chn, v);
}

// ------- classifier: reduce slots, mean, @Wc + bc -------
__global__ __launch_bounds__(64) void gat_cls(const float* __restrict__ sums,
                                              const int* __restrict__ bnds,
                                              const float* __restrict__ Wc,
                                              const float* __restrict__ bc,
                                              float* __restrict__ out) {
    int g = blockIdx.x, c = threadIdx.x;
    float s = 0.f;
#pragma unroll
    for (int sl = 0; sl < NSLOT; ++sl)
        s += sums[((size_t)sl * NG + g) * O2 + c];
    float cnt = (float)(bnds[g + 1] - bnds[g]);
    float p = s / fmaxf(cnt, 1.f);
    float p0 = p * Wc[c * 2 + 0];
    float p1 = p * Wc[c * 2 + 1];
#pragma unroll
    for (int off = 1; off < 64; off <<= 1) {
        p0 += __shfl_xor(p0, off, 64);
        p1 += __shfl_xor(p1, off, 64);
    }
    if (c == 0) {
        out[g * 2 + 0] = p0 + bc[0];
        out[g * 2 + 1] = p1 + bc[1];
    }
}

extern "C" void kernel_launch(void* const* d_in, const int* in_sizes, int n_in,
                              void* d_out, int out_size, void* d_ws, size_t ws_size,
                              hipStream_t stream) {
    const float* x   = (const float*)d_in[0];
    const int*   ei  = (const int*)d_in[1];
    const int*   bat = (const int*)d_in[2];
    const float* W1  = (const float*)d_in[3];
    const float* as1 = (const float*)d_in[4];
    const float* ad1 = (const float*)d_in[5];
    const float* b1  = (const float*)d_in[6];
    const float* W2  = (const float*)d_in[7];
    const float* as2 = (const float*)d_in[8];
    const float* ad2 = (const float*)d_in[9];
    const float* b2  = (const float*)d_in[10];
    const float* Wc  = (const float*)d_in[11];
    const float* bc  = (const float*)d_in[12];
    float* out = (float*)d_out;

    char* ws = (char*)d_ws;
    size_t off = 0;
    auto alloc = [&](size_t b) { char* p = ws + off; off += (b + 255) & ~(size_t)255; return p; };
    // bh (256 w) | gcur (256 w)  -- zeroed by gat_zero (1 block)
    int* bh   = (int*)alloc(512 * 4);
    int* gcur = bh + 256;
    // sums -- zeroed by binA's extra blocks
    float* sums = (float*)alloc((size_t)SUMW * 4);

    unsigned char*  h1f8  = (unsigned char*)alloc((size_t)NN * C1);
    unsigned short* out1b = (unsigned short*)alloc((size_t)NN * C1 * 2);
    unsigned char*  h2f8  = (unsigned char*)alloc((size_t)NN * O2);
    unsigned short* w1t   = (unsigned short*)alloc((size_t)C1 * INC * 2);
    unsigned short* w2t   = (unsigned short*)alloc((size_t)O2 * C1 * 2);
    float* aS1    = (float*)alloc((size_t)NN * 2 * 4);
    float* aD1    = (float*)alloc((size_t)NN * 2 * 4);
    float* aS2    = (float*)alloc((size_t)NN * 4);
    float* aD2    = (float*)alloc((size_t)NN * 4);
    int*   rowptr = (int*)alloc((size_t)(NN + 1) * 4);
    int*   bb     = (int*)alloc(256 * 4);
    int*   csrs   = (int*)alloc((size_t)NE * 4);
    unsigned* ebuf = (unsigned*)alloc((size_t)NE * 4);
    int*   bnds   = (int*)alloc(65 * 4);
    if (off > ws_size) return;

    // --- zero bh|gcur (tiny) ---
    gat_zero<<<1, 128, 0, stream>>>((float4*)bh);

    // --- fused prep: 196-bucket histogram | W transpose + bounds ---
    gat_prep<<<PB_HB + PB_W, 256, 0, stream>>>(ei, W1, W2, bat, bh, w1t, w2t, bnds);

    // --- bucket bases + counting sort (binA also zeroes sums) ---
    gat_scanb<<<1, 256, 0, stream>>>(bh, bb);
    gat_binA<<<NBA + SUMQ / 256, 256, 0, stream>>>(ei, bb, gcur, ebuf, (float4*)sums);
    gat_binB_gemm1<<<NBKT + (NN + 63) / 64, 256, 0, stream>>>(ebuf, bb, rowptr, csrs,
                                                              x, w1t, as1, ad1,
                                                              h1f8, aS1, aD1);

    // --- layer 1 aggregation (1 dst/wave, 2 sub-slices, no-shuffle deep-ILP gather) ---
    gat_agg1<<<NN / 4, 256, 0, stream>>>(rowptr, csrs, aS1, aD1, h1f8, out1b);

    // --- layer 2 (gemm + fused att2; fp8 h2; agg 1 dst/wave + fused pooling) ---
    gat_gemm2<<<(NN + 63) / 64, 256, 0, stream>>>(out1b, b1, w2t, as2, ad2,
                                                  h2f8, aS2, aD2);
    gat_agg2<<<NN / 4, 256, 0, stream>>>(rowptr, csrs, aS2, aD2, h2f8, bat, b2, sums);

    // --- classify ---
    gat_cls<<<NG, 64, 0, stream>>>(sums, bnds, Wc, bc, out);
}